// Round 7
// baseline (561.061 us; speedup 1.0000x reference)
//
#include <hip/hip_runtime.h>
#include <hip/hip_bf16.h>
#include <cstdint>
#include <cstddef>

#define B_  32
#define T_  2048
#define D_  1024
#define H_  1024
#define M_  (B_ * T_)   // 65536 rows of t

typedef __attribute__((ext_vector_type(4))) float  f32x4;
typedef __attribute__((ext_vector_type(8))) __bf16 bf16x8;

#define GLOBAL_AS __attribute__((address_space(1)))
#define LDS_AS    __attribute__((address_space(3)))

__device__ __forceinline__ void gload_lds16(const void* g, void* l) {
  __builtin_amdgcn_global_load_lds((const GLOBAL_AS unsigned int*)g,
                                   (LDS_AS unsigned int*)l, 16, 0, 0);
}

__device__ __forceinline__ unsigned int f2bf(float f) {
  unsigned int u = __float_as_uint(f);
  return (u + 0x7fffu + ((u >> 16) & 1u)) >> 16;   // RNE
}
__device__ __forceinline__ unsigned int packbf2(float lo, float hi) {
  return f2bf(lo) | (f2bf(hi) << 16);
}
__device__ __forceinline__ float bfu(unsigned int u) {   // bf16 bits -> f32
  return __uint_as_float(u << 16);
}
__device__ __forceinline__ float fast_tanh(float x) {
  x = fminf(fmaxf(x, -15.f), 15.f);
  float e = __expf(2.f * x);
  return (e - 1.f) / (e + 1.f);
}

// ---------------------------------------------------------------------------
// Fused prep (one dispatch, heterogeneous grid):
//   blocks [0,32):      g[b,h] GEMV, h-sliced so weights are read ONCE (16MB)
//   blocks [32,1056):   wt (DxH f32) -> wtT (HxD bf16) transpose
//   blocks [1056,5152): t (f32) -> tb (bf16) stream (HBM-bound long pole)
// g/transpose blocks are scheduled first so they hide under the stream.
// ---------------------------------------------------------------------------
__global__ __launch_bounds__(256) void k_prep_all(const float4* __restrict__ t4,
                                                  uint2* __restrict__ tb2,
                                                  const float* __restrict__ wt,
                                                  unsigned short* __restrict__ wtT,
                                                  const float* __restrict__ a,
                                                  const float* __restrict__ b,
                                                  const float* __restrict__ wa,
                                                  const float* __restrict__ wb,
                                                  const float* __restrict__ wh,
                                                  float* __restrict__ g) {
  const int bid = blockIdx.x, tid = threadIdx.x;
  if (bid < 32) {
    // ---- g: this block owns h in [h0, h0+32) for ALL 32 batches.
    // thread t: batch bb = t>>3, four consecutive h at h4.
    const int h0 = bid * 32;
    const int bb = tid >> 3;
    const int h4 = h0 + (tid & 7) * 4;
    float4 sa = make_float4(0.f, 0.f, 0.f, 0.f);
    float4 sb = make_float4(0.f, 0.f, 0.f, 0.f);
    for (int d = 0; d < 1024; ++d) {
      const float av = a[bb * 1024 + d], bv = b[bb * 1024 + d];
      const float4 wav = *(const float4*)(wa + (size_t)d * 1024 + h4);
      const float4 wbv = *(const float4*)(wb + (size_t)d * 1024 + h4);
      sa.x += av * wav.x; sa.y += av * wav.y; sa.z += av * wav.z; sa.w += av * wav.w;
      sb.x += bv * wbv.x; sb.y += bv * wbv.y; sb.z += bv * wbv.z; sb.w += bv * wbv.w;
    }
    g[bb * H_ + h4 + 0] = fast_tanh(sa.x) * fast_tanh(sb.x) * wh[h4 + 0];
    g[bb * H_ + h4 + 1] = fast_tanh(sa.y) * fast_tanh(sb.y) * wh[h4 + 1];
    g[bb * H_ + h4 + 2] = fast_tanh(sa.z) * fast_tanh(sb.z) * wh[h4 + 2];
    g[bb * H_ + h4 + 3] = fast_tanh(sa.w) * fast_tanh(sb.w) * wh[h4 + 3];
  } else if (bid < 1056) {
    // ---- wtT transpose (32x32 tiles, LDS staged)
    __shared__ float tile[32][33];
    const int tile_id = bid - 32;
    const int tx = tid & 31, ty = tid >> 5;
    const int c0 = (tile_id & 31) * 32, r0 = (tile_id >> 5) * 32;
#pragma unroll
    for (int i = 0; i < 4; ++i)
      tile[ty + i * 8][tx] = wt[(size_t)(r0 + ty + i * 8) * H_ + c0 + tx];
    __syncthreads();
#pragma unroll
    for (int i = 0; i < 4; ++i)
      wtT[(size_t)(c0 + ty + i * 8) * D_ + r0 + tx] = (unsigned short)f2bf(tile[tx][ty + i * 8]);
  } else {
    // ---- t -> bf16 stream
    const int cb = bid - 1056;                       // 0..4095
    const size_t stride = (size_t)4096 * 256;
    for (size_t i = (size_t)cb * 256 + tid; i < (size_t)M_ * 256; i += stride) {
      const float4 v = t4[i];
      uint2 o; o.x = packbf2(v.x, v.y); o.y = packbf2(v.z, v.w);
      tb2[i] = o;
    }
  }
}

// ---------------------------------------------------------------------------
// FAST fused score GEMM (r5-proven): 256x128 tile, BK=64, 8 waves (4M x 2N),
// 512 threads. global_load_lds width-16 staging with both-sides XOR swizzle
// (linear LDS dest, pre-swizzled global source chunk, same XOR on ds_read).
// XCD-bijective grid swizzle (2048 wgs). Conflicts measured 0; 167 us.
// spart[bn][row] = sum_{h in bn-block} tanh((t@wt)[row,h]) * g[b,h]
// ---------------------------------------------------------------------------
__global__ __launch_bounds__(512) void k_score_fast(const unsigned short* __restrict__ tb,
                                                    const unsigned short* __restrict__ wtT,
                                                    const float* __restrict__ g,
                                                    float* __restrict__ spart) {
  __shared__ unsigned short As[256 * 64];   // 32 KB  [row][k] linear+swz
  __shared__ unsigned short Bs[128 * 64];   // 16 KB  [n][k]  linear+swz
  __shared__ float red[512];                // [wn][256 rows]
  const int tid = threadIdx.x;
  const int wg  = (blockIdx.x & 7) * 256 + (blockIdx.x >> 3);  // bijective
  const int bm2 = wg >> 3, bn = wg & 7;
  const int lane = tid & 63, w = tid >> 6;       // 8 waves
  const int wm = w >> 1, wn = w & 1;             // 4 x 2
  const int l15 = lane & 15, lk = lane >> 4;
  const int axk = l15 & 7;                       // read-side XOR key
  const int row0 = bm2 * 256, col0 = bn * 128;

  // staging: wave-uniform LDS base + lane*16B linear dest (gload_lds req).
  // global source chunk pre-swizzled: chunk = (lane&7) ^ srow, srow = lane>>3.
  const int srow = lane >> 3;                    // 8 rows per 1KB issue
  const int scol = (((lane & 7) ^ srow) * 8);    // swizzled 16B chunk
  const unsigned short* gA = tb  + (size_t)(row0 + w * 32 + srow) * 1024 + scol;
  const unsigned short* gB = wtT + (size_t)(col0 + w * 16 + srow) * 1024 + scol;
  unsigned short* lA = &As[(w * 32) * 64];
  unsigned short* lB = &Bs[(w * 16) * 64];

  f32x4 acc[4][4] = {};

  for (int kt = 0; kt < 16; ++kt) {
    const int k0 = kt * 64;
    __syncthreads();   // previous iteration's LDS reads done
#pragma unroll
    for (int i = 0; i < 4; ++i)   // A: rows w*32 + i*8 .. +8
      gload_lds16(gA + (size_t)i * 8192 + k0, lA + i * 512);
#pragma unroll
    for (int j = 0; j < 2; ++j)   // B: rows w*16 + j*8 .. +8
      gload_lds16(gB + (size_t)j * 8192 + k0, lB + j * 512);
    __syncthreads();   // compiler drains vmcnt(0) before this barrier
#pragma unroll
    for (int kf = 0; kf < 2; ++kf) {
      bf16x8 af[4], bfr[4];
#pragma unroll
      for (int mi = 0; mi < 4; ++mi)
        af[mi] = *(const bf16x8*)(&As[(wm * 64 + mi * 16 + l15) * 64
                                      + (((kf * 4 + lk) ^ axk) << 3)]);
#pragma unroll
      for (int ni = 0; ni < 4; ++ni)
        bfr[ni] = *(const bf16x8*)(&Bs[(wn * 64 + ni * 16 + l15) * 64
                                       + (((kf * 4 + lk) ^ axk) << 3)]);
#pragma unroll
      for (int mi = 0; mi < 4; ++mi)
#pragma unroll
        for (int ni = 0; ni < 4; ++ni)
          acc[mi][ni] = __builtin_amdgcn_mfma_f32_16x16x32_bf16(af[mi], bfr[ni], acc[mi][ni], 0, 0, 0);
    }
  }

  // ---- epilogue: tanh, * g[b,h], reduce over this block's 128 h-columns
  const int b = row0 >> 11;  // 256-row tile never crosses a b-boundary
  float gv[4];
#pragma unroll
  for (int ni = 0; ni < 4; ++ni)
    gv[ni] = g[b * H_ + col0 + wn * 64 + ni * 16 + l15];
#pragma unroll
  for (int mi = 0; mi < 4; ++mi) {
#pragma unroll
    for (int r = 0; r < 4; ++r) {
      float s = 0.f;
#pragma unroll
      for (int ni = 0; ni < 4; ++ni)
        s += fast_tanh(acc[mi][ni][r]) * gv[ni];
      s += __shfl_xor(s, 1); s += __shfl_xor(s, 2);
      s += __shfl_xor(s, 4); s += __shfl_xor(s, 8);
      if (l15 == 0)
        red[wn * 256 + wm * 64 + mi * 16 + lk * 4 + r] = s;
    }
  }
  __syncthreads();
  if (tid < 256)
    spart[(size_t)bn * M_ + row0 + tid] = red[tid] + red[256 + tid];
}

// ---------------------------------------------------------------------------
// Fallback fused score GEMM (reg-staged fp32->bf16), used if ws too small.
// ---------------------------------------------------------------------------
__global__ __launch_bounds__(256) void k_score_rs(const float* __restrict__ t,
                                                  const unsigned short* __restrict__ wtT,
                                                  const float* __restrict__ g,
                                                  float* __restrict__ spart) {
  __shared__ unsigned short As[128 * 72];
  __shared__ unsigned short Bs[128 * 72];
  __shared__ float red[256];
  const int tid = threadIdx.x;
  const int bn = blockIdx.x, bm = blockIdx.y;
  const int lane = tid & 63, w = tid >> 6;
  const int wm = w >> 1, wn = w & 1;
  const int l15 = lane & 15, lk = lane >> 4;
  const int row0 = bm * 128, col0 = bn * 128;
  const int ar = tid >> 2, ac = (tid & 3) * 16;
  const int brn = tid >> 1, bco = (tid & 1) * 32;

  f32x4 acc[4][4] = {};

  for (int kt = 0; kt < 16; ++kt) {
    const int k0 = kt * 64;
    __syncthreads();
#pragma unroll
    for (int half = 0; half < 2; ++half) {
      const int r = ar + half * 64;
      const float4* src = (const float4*)(t + (size_t)(row0 + r) * 1024 + k0 + ac);
      float4 v0 = src[0], v1 = src[1], v2 = src[2], v3 = src[3];
      uint4 p0, p1;
      p0.x = packbf2(v0.x, v0.y); p0.y = packbf2(v0.z, v0.w);
      p0.z = packbf2(v1.x, v1.y); p0.w = packbf2(v1.z, v1.w);
      p1.x = packbf2(v2.x, v2.y); p1.y = packbf2(v2.z, v2.w);
      p1.z = packbf2(v3.x, v3.y); p1.w = packbf2(v3.z, v3.w);
      uint4* dst = (uint4*)(&As[r * 72 + ac]);
      dst[0] = p0; dst[1] = p1;
    }
    {
      const uint4* src = (const uint4*)(wtT + (size_t)(col0 + brn) * 1024 + k0 + bco);
      uint4 x0 = src[0], x1 = src[1], x2 = src[2], x3 = src[3];
      uint4* dst = (uint4*)(&Bs[brn * 72 + bco]);
      dst[0] = x0; dst[1] = x1; dst[2] = x2; dst[3] = x3;
    }
    __syncthreads();
#pragma unroll
    for (int kf = 0; kf < 2; ++kf) {
      bf16x8 af[4], bfr[4];
#pragma unroll
      for (int mi = 0; mi < 4; ++mi)
        af[mi] = *(const bf16x8*)(&As[(wm * 64 + mi * 16 + l15) * 72 + kf * 32 + lk * 8]);
#pragma unroll
      for (int ni = 0; ni < 4; ++ni)
        bfr[ni] = *(const bf16x8*)(&Bs[(wn * 64 + ni * 16 + l15) * 72 + kf * 32 + lk * 8]);
#pragma unroll
      for (int mi = 0; mi < 4; ++mi)
#pragma unroll
        for (int ni = 0; ni < 4; ++ni)
          acc[mi][ni] = __builtin_amdgcn_mfma_f32_16x16x32_bf16(af[mi], bfr[ni], acc[mi][ni], 0, 0, 0);
    }
  }

  const int b = row0 >> 11;
  float gv[4];
#pragma unroll
  for (int ni = 0; ni < 4; ++ni)
    gv[ni] = g[b * H_ + col0 + wn * 64 + ni * 16 + l15];
#pragma unroll
  for (int mi = 0; mi < 4; ++mi) {
#pragma unroll
    for (int r = 0; r < 4; ++r) {
      float s = 0.f;
#pragma unroll
      for (int ni = 0; ni < 4; ++ni)
        s += fast_tanh(acc[mi][ni][r]) * gv[ni];
      s += __shfl_xor(s, 1); s += __shfl_xor(s, 2);
      s += __shfl_xor(s, 4); s += __shfl_xor(s, 8);
      if (l15 == 0)
        red[wn * 128 + wm * 64 + mi * 16 + lk * 4 + r] = s;
    }
  }
  __syncthreads();
  if (tid < 128)
    spart[(size_t)bn * M_ + row0 + tid] = red[tid] + red[128 + tid];
}

// ---------------------------------------------------------------------------
// Softmax + mask + renormalize, with inline mask-layout detection.
// ---------------------------------------------------------------------------
__global__ __launch_bounds__(256) void k_softmax(const float* __restrict__ spart,
                                                 const void* __restrict__ mask,
                                                 float* __restrict__ att,
                                                 int nplanes) {
  __shared__ float redmax[4], redsum[4];
  __shared__ int shflag[4];
  const int b = blockIdx.x, tid = threadIdx.x;

  {
    const unsigned int* mw = (const unsigned int*)mask;
    int any = 0;
    for (int i = tid; i < 16384; i += 256)
      if (mw[i] > 1u) any = 1;
    const int wa = __any(any) ? 1 : 0;
    if ((tid & 63) == 0) shflag[tid >> 6] = wa;
  }

  float s[8];
#pragma unroll
  for (int j = 0; j < 8; ++j) {
    const int idx = tid + j * 256;
    float v = 0.f;
    for (int nb = 0; nb < nplanes; ++nb) v += spart[(size_t)nb * M_ + b * T_ + idx];
    s[j] = v;
  }
  float mx = s[0];
#pragma unroll
  for (int j = 1; j < 8; ++j) mx = fmaxf(mx, s[j]);
  for (int o = 1; o < 64; o <<= 1) mx = fmaxf(mx, __shfl_xor(mx, o));
  if ((tid & 63) == 0) redmax[tid >> 6] = mx;
  __syncthreads();
  mx = fmaxf(fmaxf(redmax[0], redmax[1]), fmaxf(redmax[2], redmax[3]));
  const int byte_mode = shflag[0] | shflag[1] | shflag[2] | shflag[3];

  float e[8];
  float sum = 0.f;
#pragma unroll
  for (int j = 0; j < 8; ++j) {
    const int idx = tid + j * 256;
    float v = __expf(s[j] - mx);
    const int mv = byte_mode ? (int)((const unsigned char*)mask)[b * T_ + idx]
                             : ((const int*)mask)[b * T_ + idx];
    v = (mv != 0) ? v : 0.f;
    e[j] = v;
    sum += v;
  }
  for (int o = 1; o < 64; o <<= 1) sum += __shfl_xor(sum, o);
  if ((tid & 63) == 0) redsum[tid >> 6] = sum;
  __syncthreads();
  sum = redsum[0] + redsum[1] + redsum[2] + redsum[3];
  const float inv = 1.f / sum;
#pragma unroll
  for (int j = 0; j < 8; ++j)
    att[b * T_ + tid + j * 256] = e[j] * inv;
}

// ---------------------------------------------------------------------------
// Pooling on bf16 t: pp[tc][b][d] = sum att * tb
// ---------------------------------------------------------------------------
__global__ __launch_bounds__(256) void k_pool_bf(const unsigned short* __restrict__ tb,
                                                 const float* __restrict__ att,
                                                 float* __restrict__ pp) {
  const int b = blockIdx.x, tc = blockIdx.y, tid = threadIdx.x;
  const uint2* tp = (const uint2*)tb;
  float4 acc = make_float4(0.f, 0.f, 0.f, 0.f);
  const int tbase = tc * 128;
  for (int i = 0; i < 128; ++i) {
    const int ti = tbase + i;
    const float wv = att[b * T_ + ti];
    const uint2 v = tp[(size_t)(b * T_ + ti) * 256 + tid];
    acc.x += wv * bfu(v.x & 0xffffu);
    acc.y += wv * bfu(v.x >> 16);
    acc.z += wv * bfu(v.y & 0xffffu);
    acc.w += wv * bfu(v.y >> 16);
  }
  ((float4*)pp)[(size_t)tc * 8192 + b * 256 + tid] = acc;
}

// Fallback pooling on fp32 t.
__global__ __launch_bounds__(256) void k_pool_f32(const float* __restrict__ t,
                                                  const float* __restrict__ att,
                                                  float* __restrict__ pp) {
  const int b = blockIdx.x, tc = blockIdx.y, tid = threadIdx.x;
  const float4* tp = (const float4*)t;
  float4 acc = make_float4(0.f, 0.f, 0.f, 0.f);
  const int tbase = tc * 128;
  for (int i = 0; i < 128; ++i) {
    const int ti = tbase + i;
    const float w = att[b * T_ + ti];
    const float4 v = tp[(size_t)(b * T_ + ti) * 256 + tid];
    acc.x += w * v.x; acc.y += w * v.y; acc.z += w * v.z; acc.w += w * v.w;
  }
  ((float4*)pp)[(size_t)tc * 8192 + b * 256 + tid] = acc;
}

__global__ __launch_bounds__(256) void k_pool_reduce(const float* __restrict__ pp,
                                                     float* __restrict__ out) {
  const int idx = blockIdx.x * 256 + threadIdx.x;  // 0 .. 32767
  float s = 0.f;
#pragma unroll
  for (int tc = 0; tc < 16; ++tc) s += pp[tc * 32768 + idx];
  out[idx] = s;
}

// ---------------------------------------------------------------------------
extern "C" void kernel_launch(void* const* d_in, const int* in_sizes, int n_in,
                              void* d_out, int out_size, void* d_ws, size_t ws_size,
                              hipStream_t stream) {
  const float* t    = (const float*)d_in[0];
  const float* a    = (const float*)d_in[1];
  const float* b    = (const float*)d_in[2];
  const void*  mask = d_in[3];
  const float* wt   = (const float*)d_in[4];
  const float* wa   = (const float*)d_in[5];
  const float* wb   = (const float*)d_in[6];
  const float* wh   = (const float*)d_in[7];
  float* out = (float*)d_out;

  float* ws = (float*)d_ws;
  const size_t NEED_FAST = (size_t)(33554432 + 32768 + 65536 + 524288 + 524288 + 524288) * 4;
  const bool fast = ws_size >= NEED_FAST;

  if (fast) {
    unsigned short* tb = (unsigned short*)ws;          // 128 MB
    float* g     = ws + 33554432;
    float* att   = g + 32768;
    float* spart = att + 65536;
    float* pp    = spart + 524288;
    unsigned short* wtT = (unsigned short*)(pp + 524288);

    k_prep_all<<<5152, 256, 0, stream>>>((const float4*)t, (uint2*)tb,
                                         wt, wtT, a, b, wa, wb, wh, g);
    k_score_fast<<<2048, 512, 0, stream>>>(tb, wtT, g, spart);
    k_softmax<<<32, 256, 0, stream>>>(spart, mask, att, 8);
    k_pool_bf<<<dim3(32, 16), 256, 0, stream>>>(tb, att, pp);
    k_pool_reduce<<<128, 256, 0, stream>>>(pp, out);
  } else {
    float* g     = ws;
    float* att   = ws + 32768;
    float* spart = ws + 98304;
    float* pp    = ws + 622592;
    unsigned short* wtT = (unsigned short*)(ws + 1146880);

    // prep without the tobf16 stream (blocks [0,1056) only; tb unused)
    k_prep_all<<<1056, 256, 0, stream>>>((const float4*)t, (uint2*)ws,
                                         wt, wtT, a, b, wa, wb, wh, g);
    k_score_rs<<<dim3(8, 512), 256, 0, stream>>>(t, wtT, g, spart);
    k_softmax<<<32, 256, 0, stream>>>(spart, mask, att, 8);
    k_pool_f32<<<dim3(32, 16), 256, 0, stream>>>(t, att, pp);
    k_pool_reduce<<<128, 256, 0, stream>>>(pp, out);
  }
}

// Round 8
// 387.977 us; speedup vs baseline: 1.4461x; 1.4461x over previous
//
#include <hip/hip_runtime.h>
#include <hip/hip_bf16.h>
#include <cstdint>
#include <cstddef>

#define B_  32
#define T_  2048
#define D_  1024
#define H_  1024
#define M_  (B_ * T_)   // 65536 rows of t

typedef __attribute__((ext_vector_type(4))) float  f32x4;
typedef __attribute__((ext_vector_type(8))) __bf16 bf16x8;

#define GLOBAL_AS __attribute__((address_space(1)))
#define LDS_AS    __attribute__((address_space(3)))

__device__ __forceinline__ void gload_lds16(const void* g, void* l) {
  __builtin_amdgcn_global_load_lds((const GLOBAL_AS unsigned int*)g,
                                   (LDS_AS unsigned int*)l, 16, 0, 0);
}

__device__ __forceinline__ unsigned int f2bf(float f) {
  unsigned int u = __float_as_uint(f);
  return (u + 0x7fffu + ((u >> 16) & 1u)) >> 16;   // RNE
}
__device__ __forceinline__ unsigned int packbf2(float lo, float hi) {
  return f2bf(lo) | (f2bf(hi) << 16);
}
__device__ __forceinline__ float bfu(unsigned int u) {   // bf16 bits -> f32
  return __uint_as_float(u << 16);
}
__device__ __forceinline__ float fast_tanh(float x) {
  x = fminf(fmaxf(x, -15.f), 15.f);
  float e = __expf(2.f * x);
  return (e - 1.f) / (e + 1.f);
}

// ---------------------------------------------------------------------------
// Fused prep (one dispatch, heterogeneous grid):
//   blocks [0,64):      g PARTIALS: (8 d-chunks x 8 h-slices); each thread
//                       owns 16 h-cols of one batch over 128 d -> high ILP.
//                       gpa/gpb[dc][b][h] (2 MB) overlay spart's memory.
//   blocks [64,1088):   wt (DxH f32) -> wtT (HxD bf16) transpose
//   blocks [1088,5184): t (f32) -> tb (bf16) stream (HBM-bound long pole)
// ---------------------------------------------------------------------------
__global__ __launch_bounds__(256) void k_prep_all(const float4* __restrict__ t4,
                                                  uint2* __restrict__ tb2,
                                                  const float* __restrict__ wt,
                                                  unsigned short* __restrict__ wtT,
                                                  const float* __restrict__ a,
                                                  const float* __restrict__ b,
                                                  const float* __restrict__ wa,
                                                  const float* __restrict__ wb,
                                                  float* __restrict__ gpa,
                                                  float* __restrict__ gpb) {
  const int bid = blockIdx.x, tid = threadIdx.x;
  if (bid < 64) {
    // ---- g partials: dc = d-chunk, hs = h-slice
    const int dc = bid >> 3, hs = bid & 7;
    const int d0 = dc * 128, h0 = hs * 128;
    const int bb = tid >> 3;                     // 0..31
    const int hbase = h0 + (tid & 7) * 16;       // 16 h per thread
    float4 sa0 = {0,0,0,0}, sa1 = {0,0,0,0}, sa2 = {0,0,0,0}, sa3 = {0,0,0,0};
    float4 sb0 = {0,0,0,0}, sb1 = {0,0,0,0}, sb2 = {0,0,0,0}, sb3 = {0,0,0,0};
    for (int di = 0; di < 128; ++di) {
      const int d = d0 + di;
      const float av = a[bb * 1024 + d];
      const float bv = b[bb * 1024 + d];
      const float4* wav = (const float4*)(wa + (size_t)d * 1024 + hbase);
      const float4* wbv = (const float4*)(wb + (size_t)d * 1024 + hbase);
      const float4 x0 = wav[0], x1 = wav[1], x2 = wav[2], x3 = wav[3];
      const float4 y0 = wbv[0], y1 = wbv[1], y2 = wbv[2], y3 = wbv[3];
      sa0.x += av * x0.x; sa0.y += av * x0.y; sa0.z += av * x0.z; sa0.w += av * x0.w;
      sa1.x += av * x1.x; sa1.y += av * x1.y; sa1.z += av * x1.z; sa1.w += av * x1.w;
      sa2.x += av * x2.x; sa2.y += av * x2.y; sa2.z += av * x2.z; sa2.w += av * x2.w;
      sa3.x += av * x3.x; sa3.y += av * x3.y; sa3.z += av * x3.z; sa3.w += av * x3.w;
      sb0.x += bv * y0.x; sb0.y += bv * y0.y; sb0.z += bv * y0.z; sb0.w += bv * y0.w;
      sb1.x += bv * y1.x; sb1.y += bv * y1.y; sb1.z += bv * y1.z; sb1.w += bv * y1.w;
      sb2.x += bv * y2.x; sb2.y += bv * y2.y; sb2.z += bv * y2.z; sb2.w += bv * y2.w;
      sb3.x += bv * y3.x; sb3.y += bv * y3.y; sb3.z += bv * y3.z; sb3.w += bv * y3.w;
    }
    float4* pa = (float4*)(gpa + (size_t)dc * 32768 + bb * 1024 + hbase);
    float4* pb = (float4*)(gpb + (size_t)dc * 32768 + bb * 1024 + hbase);
    pa[0] = sa0; pa[1] = sa1; pa[2] = sa2; pa[3] = sa3;
    pb[0] = sb0; pb[1] = sb1; pb[2] = sb2; pb[3] = sb3;
  } else if (bid < 1088) {
    // ---- wtT transpose (32x32 tiles, LDS staged)
    __shared__ float tile[32][33];
    const int tile_id = bid - 64;
    const int tx = tid & 31, ty = tid >> 5;
    const int c0 = (tile_id & 31) * 32, r0 = (tile_id >> 5) * 32;
#pragma unroll
    for (int i = 0; i < 4; ++i)
      tile[ty + i * 8][tx] = wt[(size_t)(r0 + ty + i * 8) * H_ + c0 + tx];
    __syncthreads();
#pragma unroll
    for (int i = 0; i < 4; ++i)
      wtT[(size_t)(c0 + ty + i * 8) * D_ + r0 + tx] = (unsigned short)f2bf(tile[tx][ty + i * 8]);
  } else {
    // ---- t -> bf16 stream
    const int cb = bid - 1088;                       // 0..4095
    const size_t stride = (size_t)4096 * 256;
    for (size_t i = (size_t)cb * 256 + tid; i < (size_t)M_ * 256; i += stride) {
      const float4 v = t4[i];
      uint2 o; o.x = packbf2(v.x, v.y); o.y = packbf2(v.z, v.w);
      tb2[i] = o;
    }
  }
}

// ---------------------------------------------------------------------------
// g finalize: g[b,h] = tanh(sum gpa) * tanh(sum gpb) * wh[h]
// ---------------------------------------------------------------------------
__global__ __launch_bounds__(256) void k_gfin(const float* __restrict__ gpa,
                                              const float* __restrict__ gpb,
                                              const float* __restrict__ wh,
                                              float* __restrict__ g) {
  const int idx = blockIdx.x * 256 + threadIdx.x;  // 0..32767
  float sa = 0.f, sb = 0.f;
#pragma unroll
  for (int dc = 0; dc < 8; ++dc) {
    sa += gpa[(size_t)dc * 32768 + idx];
    sb += gpb[(size_t)dc * 32768 + idx];
  }
  g[idx] = fast_tanh(sa) * fast_tanh(sb) * wh[idx & 1023];
}

// ---------------------------------------------------------------------------
// FAST fused score GEMM (r5-proven, UNTOUCHED): 256x128 tile, BK=64,
// 8 waves (4M x 2N), 512 threads, gload_lds + both-sides XOR swizzle,
// XCD-bijective grid swizzle. 167 us, conflicts 0, MfmaUtil 36%.
// ---------------------------------------------------------------------------
__global__ __launch_bounds__(512) void k_score_fast(const unsigned short* __restrict__ tb,
                                                    const unsigned short* __restrict__ wtT,
                                                    const float* __restrict__ g,
                                                    float* __restrict__ spart) {
  __shared__ unsigned short As[256 * 64];   // 32 KB  [row][k] linear+swz
  __shared__ unsigned short Bs[128 * 64];   // 16 KB  [n][k]  linear+swz
  __shared__ float red[512];                // [wn][256 rows]
  const int tid = threadIdx.x;
  const int wg  = (blockIdx.x & 7) * 256 + (blockIdx.x >> 3);  // bijective
  const int bm2 = wg >> 3, bn = wg & 7;
  const int lane = tid & 63, w = tid >> 6;       // 8 waves
  const int wm = w >> 1, wn = w & 1;             // 4 x 2
  const int l15 = lane & 15, lk = lane >> 4;
  const int axk = l15 & 7;                       // read-side XOR key
  const int row0 = bm2 * 256, col0 = bn * 128;

  const int srow = lane >> 3;                    // 8 rows per 1KB issue
  const int scol = (((lane & 7) ^ srow) * 8);    // swizzled 16B chunk
  const unsigned short* gA = tb  + (size_t)(row0 + w * 32 + srow) * 1024 + scol;
  const unsigned short* gB = wtT + (size_t)(col0 + w * 16 + srow) * 1024 + scol;
  unsigned short* lA = &As[(w * 32) * 64];
  unsigned short* lB = &Bs[(w * 16) * 64];

  f32x4 acc[4][4] = {};

  for (int kt = 0; kt < 16; ++kt) {
    const int k0 = kt * 64;
    __syncthreads();
#pragma unroll
    for (int i = 0; i < 4; ++i)
      gload_lds16(gA + (size_t)i * 8192 + k0, lA + i * 512);
#pragma unroll
    for (int j = 0; j < 2; ++j)
      gload_lds16(gB + (size_t)j * 8192 + k0, lB + j * 512);
    __syncthreads();
#pragma unroll
    for (int kf = 0; kf < 2; ++kf) {
      bf16x8 af[4], bfr[4];
#pragma unroll
      for (int mi = 0; mi < 4; ++mi)
        af[mi] = *(const bf16x8*)(&As[(wm * 64 + mi * 16 + l15) * 64
                                      + (((kf * 4 + lk) ^ axk) << 3)]);
#pragma unroll
      for (int ni = 0; ni < 4; ++ni)
        bfr[ni] = *(const bf16x8*)(&Bs[(wn * 64 + ni * 16 + l15) * 64
                                       + (((kf * 4 + lk) ^ axk) << 3)]);
#pragma unroll
      for (int mi = 0; mi < 4; ++mi)
#pragma unroll
        for (int ni = 0; ni < 4; ++ni)
          acc[mi][ni] = __builtin_amdgcn_mfma_f32_16x16x32_bf16(af[mi], bfr[ni], acc[mi][ni], 0, 0, 0);
    }
  }

  const int b = row0 >> 11;
  float gv[4];
#pragma unroll
  for (int ni = 0; ni < 4; ++ni)
    gv[ni] = g[b * H_ + col0 + wn * 64 + ni * 16 + l15];
#pragma unroll
  for (int mi = 0; mi < 4; ++mi) {
#pragma unroll
    for (int r = 0; r < 4; ++r) {
      float s = 0.f;
#pragma unroll
      for (int ni = 0; ni < 4; ++ni)
        s += fast_tanh(acc[mi][ni][r]) * gv[ni];
      s += __shfl_xor(s, 1); s += __shfl_xor(s, 2);
      s += __shfl_xor(s, 4); s += __shfl_xor(s, 8);
      if (l15 == 0)
        red[wn * 256 + wm * 64 + mi * 16 + lk * 4 + r] = s;
    }
  }
  __syncthreads();
  if (tid < 256)
    spart[(size_t)bn * M_ + row0 + tid] = red[tid] + red[256 + tid];
}

// ---------------------------------------------------------------------------
// Fallback fused score GEMM (reg-staged fp32->bf16), used if ws too small.
// ---------------------------------------------------------------------------
__global__ __launch_bounds__(256) void k_score_rs(const float* __restrict__ t,
                                                  const unsigned short* __restrict__ wtT,
                                                  const float* __restrict__ g,
                                                  float* __restrict__ spart) {
  __shared__ unsigned short As[128 * 72];
  __shared__ unsigned short Bs[128 * 72];
  __shared__ float red[256];
  const int tid = threadIdx.x;
  const int bn = blockIdx.x, bm = blockIdx.y;
  const int lane = tid & 63, w = tid >> 6;
  const int wm = w >> 1, wn = w & 1;
  const int l15 = lane & 15, lk = lane >> 4;
  const int row0 = bm * 128, col0 = bn * 128;
  const int ar = tid >> 2, ac = (tid & 3) * 16;
  const int brn = tid >> 1, bco = (tid & 1) * 32;

  f32x4 acc[4][4] = {};

  for (int kt = 0; kt < 16; ++kt) {
    const int k0 = kt * 64;
    __syncthreads();
#pragma unroll
    for (int half = 0; half < 2; ++half) {
      const int r = ar + half * 64;
      const float4* src = (const float4*)(t + (size_t)(row0 + r) * 1024 + k0 + ac);
      float4 v0 = src[0], v1 = src[1], v2 = src[2], v3 = src[3];
      uint4 p0, p1;
      p0.x = packbf2(v0.x, v0.y); p0.y = packbf2(v0.z, v0.w);
      p0.z = packbf2(v1.x, v1.y); p0.w = packbf2(v1.z, v1.w);
      p1.x = packbf2(v2.x, v2.y); p1.y = packbf2(v2.z, v2.w);
      p1.z = packbf2(v3.x, v3.y); p1.w = packbf2(v3.z, v3.w);
      uint4* dst = (uint4*)(&As[r * 72 + ac]);
      dst[0] = p0; dst[1] = p1;
    }
    {
      const uint4* src = (const uint4*)(wtT + (size_t)(col0 + brn) * 1024 + k0 + bco);
      uint4 x0 = src[0], x1 = src[1], x2 = src[2], x3 = src[3];
      uint4* dst = (uint4*)(&Bs[brn * 72 + bco]);
      dst[0] = x0; dst[1] = x1; dst[2] = x2; dst[3] = x3;
    }
    __syncthreads();
#pragma unroll
    for (int kf = 0; kf < 2; ++kf) {
      bf16x8 af[4], bfr[4];
#pragma unroll
      for (int mi = 0; mi < 4; ++mi)
        af[mi] = *(const bf16x8*)(&As[(wm * 64 + mi * 16 + l15) * 72 + kf * 32 + lk * 8]);
#pragma unroll
      for (int ni = 0; ni < 4; ++ni)
        bfr[ni] = *(const bf16x8*)(&Bs[(wn * 64 + ni * 16 + l15) * 72 + kf * 32 + lk * 8]);
#pragma unroll
      for (int mi = 0; mi < 4; ++mi)
#pragma unroll
        for (int ni = 0; ni < 4; ++ni)
          acc[mi][ni] = __builtin_amdgcn_mfma_f32_16x16x32_bf16(af[mi], bfr[ni], acc[mi][ni], 0, 0, 0);
    }
  }

  const int b = row0 >> 11;
  float gv[4];
#pragma unroll
  for (int ni = 0; ni < 4; ++ni)
    gv[ni] = g[b * H_ + col0 + wn * 64 + ni * 16 + l15];
#pragma unroll
  for (int mi = 0; mi < 4; ++mi) {
#pragma unroll
    for (int r = 0; r < 4; ++r) {
      float s = 0.f;
#pragma unroll
      for (int ni = 0; ni < 4; ++ni)
        s += fast_tanh(acc[mi][ni][r]) * gv[ni];
      s += __shfl_xor(s, 1); s += __shfl_xor(s, 2);
      s += __shfl_xor(s, 4); s += __shfl_xor(s, 8);
      if (l15 == 0)
        red[wn * 128 + wm * 64 + mi * 16 + lk * 4 + r] = s;
    }
  }
  __syncthreads();
  if (tid < 128)
    spart[(size_t)bn * M_ + row0 + tid] = red[tid] + red[128 + tid];
}

// ---------------------------------------------------------------------------
// Softmax + mask + renormalize, with inline mask-layout detection.
// ---------------------------------------------------------------------------
__global__ __launch_bounds__(256) void k_softmax(const float* __restrict__ spart,
                                                 const void* __restrict__ mask,
                                                 float* __restrict__ att,
                                                 int nplanes) {
  __shared__ float redmax[4], redsum[4];
  __shared__ int shflag[4];
  const int b = blockIdx.x, tid = threadIdx.x;

  {
    const unsigned int* mw = (const unsigned int*)mask;
    int any = 0;
    for (int i = tid; i < 16384; i += 256)
      if (mw[i] > 1u) any = 1;
    const int wa = __any(any) ? 1 : 0;
    if ((tid & 63) == 0) shflag[tid >> 6] = wa;
  }

  float s[8];
#pragma unroll
  for (int j = 0; j < 8; ++j) {
    const int idx = tid + j * 256;
    float v = 0.f;
    for (int nb = 0; nb < nplanes; ++nb) v += spart[(size_t)nb * M_ + b * T_ + idx];
    s[j] = v;
  }
  float mx = s[0];
#pragma unroll
  for (int j = 1; j < 8; ++j) mx = fmaxf(mx, s[j]);
  for (int o = 1; o < 64; o <<= 1) mx = fmaxf(mx, __shfl_xor(mx, o));
  if ((tid & 63) == 0) redmax[tid >> 6] = mx;
  __syncthreads();
  mx = fmaxf(fmaxf(redmax[0], redmax[1]), fmaxf(redmax[2], redmax[3]));
  const int byte_mode = shflag[0] | shflag[1] | shflag[2] | shflag[3];

  float e[8];
  float sum = 0.f;
#pragma unroll
  for (int j = 0; j < 8; ++j) {
    const int idx = tid + j * 256;
    float v = __expf(s[j] - mx);
    const int mv = byte_mode ? (int)((const unsigned char*)mask)[b * T_ + idx]
                             : ((const int*)mask)[b * T_ + idx];
    v = (mv != 0) ? v : 0.f;
    e[j] = v;
    sum += v;
  }
  for (int o = 1; o < 64; o <<= 1) sum += __shfl_xor(sum, o);
  if ((tid & 63) == 0) redsum[tid >> 6] = sum;
  __syncthreads();
  sum = redsum[0] + redsum[1] + redsum[2] + redsum[3];
  const float inv = 1.f / sum;
#pragma unroll
  for (int j = 0; j < 8; ++j)
    att[b * T_ + tid + j * 256] = e[j] * inv;
}

// ---------------------------------------------------------------------------
// Pooling on bf16 t: pp[tc][b][d] = sum att * tb
// ---------------------------------------------------------------------------
__global__ __launch_bounds__(256) void k_pool_bf(const unsigned short* __restrict__ tb,
                                                 const float* __restrict__ att,
                                                 float* __restrict__ pp) {
  const int b = blockIdx.x, tc = blockIdx.y, tid = threadIdx.x;
  const uint2* tp = (const uint2*)tb;
  float4 acc = make_float4(0.f, 0.f, 0.f, 0.f);
  const int tbase = tc * 128;
  for (int i = 0; i < 128; ++i) {
    const int ti = tbase + i;
    const float wv = att[b * T_ + ti];
    const uint2 v = tp[(size_t)(b * T_ + ti) * 256 + tid];
    acc.x += wv * bfu(v.x & 0xffffu);
    acc.y += wv * bfu(v.x >> 16);
    acc.z += wv * bfu(v.y & 0xffffu);
    acc.w += wv * bfu(v.y >> 16);
  }
  ((float4*)pp)[(size_t)tc * 8192 + b * 256 + tid] = acc;
}

// Fallback pooling on fp32 t.
__global__ __launch_bounds__(256) void k_pool_f32(const float* __restrict__ t,
                                                  const float* __restrict__ att,
                                                  float* __restrict__ pp) {
  const int b = blockIdx.x, tc = blockIdx.y, tid = threadIdx.x;
  const float4* tp = (const float4*)t;
  float4 acc = make_float4(0.f, 0.f, 0.f, 0.f);
  const int tbase = tc * 128;
  for (int i = 0; i < 128; ++i) {
    const int ti = tbase + i;
    const float w = att[b * T_ + ti];
    const float4 v = tp[(size_t)(b * T_ + ti) * 256 + tid];
    acc.x += w * v.x; acc.y += w * v.y; acc.z += w * v.z; acc.w += w * v.w;
  }
  ((float4*)pp)[(size_t)tc * 8192 + b * 256 + tid] = acc;
}

__global__ __launch_bounds__(256) void k_pool_reduce(const float* __restrict__ pp,
                                                     float* __restrict__ out) {
  const int idx = blockIdx.x * 256 + threadIdx.x;  // 0 .. 32767
  float s = 0.f;
#pragma unroll
  for (int tc = 0; tc < 16; ++tc) s += pp[tc * 32768 + idx];
  out[idx] = s;
}

// ---------------------------------------------------------------------------
extern "C" void kernel_launch(void* const* d_in, const int* in_sizes, int n_in,
                              void* d_out, int out_size, void* d_ws, size_t ws_size,
                              hipStream_t stream) {
  const float* t    = (const float*)d_in[0];
  const float* a    = (const float*)d_in[1];
  const float* b    = (const float*)d_in[2];
  const void*  mask = d_in[3];
  const float* wt   = (const float*)d_in[4];
  const float* wa   = (const float*)d_in[5];
  const float* wb   = (const float*)d_in[6];
  const float* wh   = (const float*)d_in[7];
  float* out = (float*)d_out;

  float* ws = (float*)d_ws;
  const size_t NEED_FAST = (size_t)(33554432 + 32768 + 65536 + 524288 + 524288 + 524288) * 4;
  const bool fast = ws_size >= NEED_FAST;

  if (fast) {
    unsigned short* tb = (unsigned short*)ws;          // 128 MB
    float* g     = ws + 33554432;
    float* att   = g + 32768;
    float* spart = att + 65536;                        // 524288 floats
    float* pp    = spart + 524288;
    unsigned short* wtT = (unsigned short*)(pp + 524288);
    // gpa/gpb overlay spart: written by prep, consumed by k_gfin BEFORE
    // k_score overwrites spart. 8*32768 floats each.
    float* gpa = spart;
    float* gpb = spart + 262144;

    k_prep_all<<<5184, 256, 0, stream>>>((const float4*)t, (uint2*)tb,
                                         wt, wtT, a, b, wa, wb, gpa, gpb);
    k_gfin<<<128, 256, 0, stream>>>(gpa, gpb, wh, g);
    k_score_fast<<<2048, 512, 0, stream>>>(tb, wtT, g, spart);
    k_softmax<<<32, 256, 0, stream>>>(spart, mask, att, 8);
    k_pool_bf<<<dim3(32, 16), 256, 0, stream>>>(tb, att, pp);
    k_pool_reduce<<<128, 256, 0, stream>>>(pp, out);
  } else {
    float* g     = ws;
    float* att   = ws + 32768;
    float* spart = ws + 98304;                         // 524288 floats
    float* pp    = ws + 622592;
    unsigned short* wtT = (unsigned short*)(ws + 1146880);
    float* gpa = spart;
    float* gpb = spart + 262144;

    // prep without the tobf16 stream (blocks [0,1088) only; tb unused)
    k_prep_all<<<1088, 256, 0, stream>>>((const float4*)t, (uint2*)ws,
                                         wt, wtT, a, b, wa, wb, gpa, gpb);
    k_gfin<<<128, 256, 0, stream>>>(gpa, gpb, wh, g);
    k_score_rs<<<dim3(8, 512), 256, 0, stream>>>(t, wtT, g, spart);
    k_softmax<<<32, 256, 0, stream>>>(spart, mask, att, 8);
    k_pool_f32<<<dim3(32, 16), 256, 0, stream>>>(t, att, pp);
    k_pool_reduce<<<128, 256, 0, stream>>>(pp, out);
  }
}

// Round 10
// 278.079 us; speedup vs baseline: 2.0176x; 1.3952x over previous
//
#include <hip/hip_runtime.h>
#include <hip/hip_bf16.h>
#include <cstdint>
#include <cstddef>

#define B_  32
#define T_  2048
#define D_  1024
#define H_  1024
#define M_  (B_ * T_)   // 65536 rows of t

typedef __attribute__((ext_vector_type(4))) float  f32x4;
typedef __attribute__((ext_vector_type(8))) __bf16 bf16x8;

#define GLOBAL_AS __attribute__((address_space(1)))
#define LDS_AS    __attribute__((address_space(3)))

__device__ __forceinline__ void gload_lds16(const void* g, void* l) {
  __builtin_amdgcn_global_load_lds((const GLOBAL_AS unsigned int*)g,
                                   (LDS_AS unsigned int*)l, 16, 0, 0);
}

__device__ __forceinline__ unsigned int f2bf(float f) {
  unsigned int u = __float_as_uint(f);
  return (u + 0x7fffu + ((u >> 16) & 1u)) >> 16;   // RNE
}
__device__ __forceinline__ unsigned int packbf2(float lo, float hi) {
  return f2bf(lo) | (f2bf(hi) << 16);
}
__device__ __forceinline__ float bfu(unsigned int u) {   // bf16 bits -> f32
  return __uint_as_float(u << 16);
}
__device__ __forceinline__ float fast_tanh(float x) {
  x = fminf(fmaxf(x, -15.f), 15.f);
  float e = __expf(2.f * x);
  return (e - 1.f) / (e + 1.f);
}

// ---------------------------------------------------------------------------
// Prep (small): blocks [0,512): g partials, (dc 16 x hs 32); each thread
// owns 4 h-cols of ONE batch over 64 d -> 8 VGPR acc, 2 vec loads/iter,
// unroll 8 => deep MLP at low register pressure (r8 lesson: the fused
// kernel's 40-VGPR allocation serialized a 64-VGPR-accumulator branch).
// blocks [512,1536): wt (DxH f32) -> wtT (HxD bf16) transpose.
// gpa/gpb (2 MB each) overlay spart/pp; consumed by k_gfin before reuse.
// ---------------------------------------------------------------------------
__global__ __launch_bounds__(256) void k_prep_small(const float* __restrict__ wt,
                                                    unsigned short* __restrict__ wtT,
                                                    const float* __restrict__ a,
                                                    const float* __restrict__ b,
                                                    const float* __restrict__ wa,
                                                    const float* __restrict__ wb,
                                                    float* __restrict__ gpa,
                                                    float* __restrict__ gpb) {
  const int bid = blockIdx.x, tid = threadIdx.x;
  if (bid < 512) {
    const int dc = bid >> 5, hs = bid & 31;      // 16 d-chunks x 32 h-slices
    const int d0 = dc * 64;
    const int bb = tid >> 3;                     // 0..31
    const int h4 = hs * 32 + (tid & 7) * 4;      // 4 h per thread
    f32x4 sa = {0.f, 0.f, 0.f, 0.f}, sb = {0.f, 0.f, 0.f, 0.f};
#pragma unroll 8
    for (int di = 0; di < 64; ++di) {
      const int d = d0 + di;
      const float av = a[bb * 1024 + d];
      const float bv = b[bb * 1024 + d];
      const f32x4 wav = *(const f32x4*)(wa + (size_t)d * 1024 + h4);
      const f32x4 wbv = *(const f32x4*)(wb + (size_t)d * 1024 + h4);
      sa += av * wav;
      sb += bv * wbv;
    }
    *(f32x4*)(gpa + (size_t)dc * 32768 + bb * 1024 + h4) = sa;
    *(f32x4*)(gpb + (size_t)dc * 32768 + bb * 1024 + h4) = sb;
  } else {
    __shared__ float tile[32][33];
    const int tile_id = bid - 512;               // 0..1023
    const int tx = tid & 31, ty = tid >> 5;
    const int c0 = (tile_id & 31) * 32, r0 = (tile_id >> 5) * 32;
#pragma unroll
    for (int i = 0; i < 4; ++i)
      tile[ty + i * 8][tx] = wt[(size_t)(r0 + ty + i * 8) * H_ + c0 + tx];
    __syncthreads();
#pragma unroll
    for (int i = 0; i < 4; ++i)
      wtT[(size_t)(c0 + ty + i * 8) * D_ + r0 + tx] = (unsigned short)f2bf(tile[tx][ty + i * 8]);
  }
}

// ---------------------------------------------------------------------------
// g finalize: g[b,h] = tanh(sum_dc gpa) * tanh(sum_dc gpb) * wh[h]
// ---------------------------------------------------------------------------
__global__ __launch_bounds__(256) void k_gfin(const float* __restrict__ gpa,
                                              const float* __restrict__ gpb,
                                              const float* __restrict__ wh,
                                              float* __restrict__ g) {
  const int idx = blockIdx.x * 256 + threadIdx.x;  // 0..32767
  float sa = 0.f, sb = 0.f;
#pragma unroll
  for (int dc = 0; dc < 16; ++dc) {
    sa += gpa[(size_t)dc * 32768 + idx];
    sb += gpb[(size_t)dc * 32768 + idx];
  }
  g[idx] = fast_tanh(sa) * fast_tanh(sb) * wh[idx & 1023];
}

// ---------------------------------------------------------------------------
// t (fp32) -> t_bf16 stream. Nontemporal loads (t never re-read by this
// pass's consumers from L2 perspective); normal stores (tb re-read by score).
// ---------------------------------------------------------------------------
__global__ __launch_bounds__(256) void k_tobf16(const float* __restrict__ t,
                                                uint2* __restrict__ ob) {
  const f32x4* t4 = (const f32x4*)t;
  const size_t stride = (size_t)2048 * 256;
  size_t i = (size_t)blockIdx.x * 256 + threadIdx.x;
#pragma unroll 4
  for (; i < (size_t)M_ * 256; i += stride) {
    const f32x4 v = __builtin_nontemporal_load(&t4[i]);
    uint2 o; o.x = packbf2(v.x, v.y); o.y = packbf2(v.z, v.w);
    ob[i] = o;
  }
}

// ---------------------------------------------------------------------------
// FAST fused score GEMM (r5-proven, UNTOUCHED): 256x128 tile, BK=64,
// 8 waves (4M x 2N), 512 threads, gload_lds + both-sides XOR swizzle,
// XCD-bijective grid swizzle. 167 us, conflicts 0, MfmaUtil 36%.
// ---------------------------------------------------------------------------
__global__ __launch_bounds__(512) void k_score_fast(const unsigned short* __restrict__ tb,
                                                    const unsigned short* __restrict__ wtT,
                                                    const float* __restrict__ g,
                                                    float* __restrict__ spart) {
  __shared__ unsigned short As[256 * 64];   // 32 KB  [row][k] linear+swz
  __shared__ unsigned short Bs[128 * 64];   // 16 KB  [n][k]  linear+swz
  __shared__ float red[512];                // [wn][256 rows]
  const int tid = threadIdx.x;
  const int wg  = (blockIdx.x & 7) * 256 + (blockIdx.x >> 3);  // bijective
  const int bm2 = wg >> 3, bn = wg & 7;
  const int lane = tid & 63, w = tid >> 6;       // 8 waves
  const int wm = w >> 1, wn = w & 1;             // 4 x 2
  const int l15 = lane & 15, lk = lane >> 4;
  const int axk = l15 & 7;                       // read-side XOR key
  const int row0 = bm2 * 256, col0 = bn * 128;

  const int srow = lane >> 3;                    // 8 rows per 1KB issue
  const int scol = (((lane & 7) ^ srow) * 8);    // swizzled 16B chunk
  const unsigned short* gA = tb  + (size_t)(row0 + w * 32 + srow) * 1024 + scol;
  const unsigned short* gB = wtT + (size_t)(col0 + w * 16 + srow) * 1024 + scol;
  unsigned short* lA = &As[(w * 32) * 64];
  unsigned short* lB = &Bs[(w * 16) * 64];

  f32x4 acc[4][4] = {};

  for (int kt = 0; kt < 16; ++kt) {
    const int k0 = kt * 64;
    __syncthreads();
#pragma unroll
    for (int i = 0; i < 4; ++i)
      gload_lds16(gA + (size_t)i * 8192 + k0, lA + i * 512);
#pragma unroll
    for (int j = 0; j < 2; ++j)
      gload_lds16(gB + (size_t)j * 8192 + k0, lB + j * 512);
    __syncthreads();
#pragma unroll
    for (int kf = 0; kf < 2; ++kf) {
      bf16x8 af[4], bfr[4];
#pragma unroll
      for (int mi = 0; mi < 4; ++mi)
        af[mi] = *(const bf16x8*)(&As[(wm * 64 + mi * 16 + l15) * 64
                                      + (((kf * 4 + lk) ^ axk) << 3)]);
#pragma unroll
      for (int ni = 0; ni < 4; ++ni)
        bfr[ni] = *(const bf16x8*)(&Bs[(wn * 64 + ni * 16 + l15) * 64
                                       + (((kf * 4 + lk) ^ axk) << 3)]);
#pragma unroll
      for (int mi = 0; mi < 4; ++mi)
#pragma unroll
        for (int ni = 0; ni < 4; ++ni)
          acc[mi][ni] = __builtin_amdgcn_mfma_f32_16x16x32_bf16(af[mi], bfr[ni], acc[mi][ni], 0, 0, 0);
    }
  }

  const int b = row0 >> 11;
  float gv[4];
#pragma unroll
  for (int ni = 0; ni < 4; ++ni)
    gv[ni] = g[b * H_ + col0 + wn * 64 + ni * 16 + l15];
#pragma unroll
  for (int mi = 0; mi < 4; ++mi) {
#pragma unroll
    for (int r = 0; r < 4; ++r) {
      float s = 0.f;
#pragma unroll
      for (int ni = 0; ni < 4; ++ni)
        s += fast_tanh(acc[mi][ni][r]) * gv[ni];
      s += __shfl_xor(s, 1); s += __shfl_xor(s, 2);
      s += __shfl_xor(s, 4); s += __shfl_xor(s, 8);
      if (l15 == 0)
        red[wn * 256 + wm * 64 + mi * 16 + lk * 4 + r] = s;
    }
  }
  __syncthreads();
  if (tid < 256)
    spart[(size_t)bn * M_ + row0 + tid] = red[tid] + red[256 + tid];
}

// ---------------------------------------------------------------------------
// Fallback fused score GEMM (reg-staged fp32->bf16), used if ws too small.
// ---------------------------------------------------------------------------
__global__ __launch_bounds__(256) void k_score_rs(const float* __restrict__ t,
                                                  const unsigned short* __restrict__ wtT,
                                                  const float* __restrict__ g,
                                                  float* __restrict__ spart) {
  __shared__ unsigned short As[128 * 72];
  __shared__ unsigned short Bs[128 * 72];
  __shared__ float red[256];
  const int tid = threadIdx.x;
  const int bn = blockIdx.x, bm = blockIdx.y;
  const int lane = tid & 63, w = tid >> 6;
  const int wm = w >> 1, wn = w & 1;
  const int l15 = lane & 15, lk = lane >> 4;
  const int row0 = bm * 128, col0 = bn * 128;
  const int ar = tid >> 2, ac = (tid & 3) * 16;
  const int brn = tid >> 1, bco = (tid & 1) * 32;

  f32x4 acc[4][4] = {};

  for (int kt = 0; kt < 16; ++kt) {
    const int k0 = kt * 64;
    __syncthreads();
#pragma unroll
    for (int half = 0; half < 2; ++half) {
      const int r = ar + half * 64;
      const float4* src = (const float4*)(t + (size_t)(row0 + r) * 1024 + k0 + ac);
      float4 v0 = src[0], v1 = src[1], v2 = src[2], v3 = src[3];
      uint4 p0, p1;
      p0.x = packbf2(v0.x, v0.y); p0.y = packbf2(v0.z, v0.w);
      p0.z = packbf2(v1.x, v1.y); p0.w = packbf2(v1.z, v1.w);
      p1.x = packbf2(v2.x, v2.y); p1.y = packbf2(v2.z, v2.w);
      p1.z = packbf2(v3.x, v3.y); p1.w = packbf2(v3.z, v3.w);
      uint4* dst = (uint4*)(&As[r * 72 + ac]);
      dst[0] = p0; dst[1] = p1;
    }
    {
      const uint4* src = (const uint4*)(wtT + (size_t)(col0 + brn) * 1024 + k0 + bco);
      uint4 x0 = src[0], x1 = src[1], x2 = src[2], x3 = src[3];
      uint4* dst = (uint4*)(&Bs[brn * 72 + bco]);
      dst[0] = x0; dst[1] = x1; dst[2] = x2; dst[3] = x3;
    }
    __syncthreads();
#pragma unroll
    for (int kf = 0; kf < 2; ++kf) {
      bf16x8 af[4], bfr[4];
#pragma unroll
      for (int mi = 0; mi < 4; ++mi)
        af[mi] = *(const bf16x8*)(&As[(wm * 64 + mi * 16 + l15) * 72 + kf * 32 + lk * 8]);
#pragma unroll
      for (int ni = 0; ni < 4; ++ni)
        bfr[ni] = *(const bf16x8*)(&Bs[(wn * 64 + ni * 16 + l15) * 72 + kf * 32 + lk * 8]);
#pragma unroll
      for (int mi = 0; mi < 4; ++mi)
#pragma unroll
        for (int ni = 0; ni < 4; ++ni)
          acc[mi][ni] = __builtin_amdgcn_mfma_f32_16x16x32_bf16(af[mi], bfr[ni], acc[mi][ni], 0, 0, 0);
    }
  }

  const int b = row0 >> 11;
  float gv[4];
#pragma unroll
  for (int ni = 0; ni < 4; ++ni)
    gv[ni] = g[b * H_ + col0 + wn * 64 + ni * 16 + l15];
#pragma unroll
  for (int mi = 0; mi < 4; ++mi) {
#pragma unroll
    for (int r = 0; r < 4; ++r) {
      float s = 0.f;
#pragma unroll
      for (int ni = 0; ni < 4; ++ni)
        s += fast_tanh(acc[mi][ni][r]) * gv[ni];
      s += __shfl_xor(s, 1); s += __shfl_xor(s, 2);
      s += __shfl_xor(s, 4); s += __shfl_xor(s, 8);
      if (l15 == 0)
        red[wn * 128 + wm * 64 + mi * 16 + lk * 4 + r] = s;
    }
  }
  __syncthreads();
  if (tid < 128)
    spart[(size_t)bn * M_ + row0 + tid] = red[tid] + red[128 + tid];
}

// ---------------------------------------------------------------------------
// Softmax + mask + renormalize, with inline mask-layout detection.
// ---------------------------------------------------------------------------
__global__ __launch_bounds__(256) void k_softmax(const float* __restrict__ spart,
                                                 const void* __restrict__ mask,
                                                 float* __restrict__ att,
                                                 int nplanes) {
  __shared__ float redmax[4], redsum[4];
  __shared__ int shflag[4];
  const int b = blockIdx.x, tid = threadIdx.x;

  {
    const unsigned int* mw = (const unsigned int*)mask;
    int any = 0;
    for (int i = tid; i < 16384; i += 256)
      if (mw[i] > 1u) any = 1;
    const int wa = __any(any) ? 1 : 0;
    if ((tid & 63) == 0) shflag[tid >> 6] = wa;
  }

  float s[8];
#pragma unroll
  for (int j = 0; j < 8; ++j) {
    const int idx = tid + j * 256;
    float v = 0.f;
    for (int nb = 0; nb < nplanes; ++nb) v += spart[(size_t)nb * M_ + b * T_ + idx];
    s[j] = v;
  }
  float mx = s[0];
#pragma unroll
  for (int j = 1; j < 8; ++j) mx = fmaxf(mx, s[j]);
  for (int o = 1; o < 64; o <<= 1) mx = fmaxf(mx, __shfl_xor(mx, o));
  if ((tid & 63) == 0) redmax[tid >> 6] = mx;
  __syncthreads();
  mx = fmaxf(fmaxf(redmax[0], redmax[1]), fmaxf(redmax[2], redmax[3]));
  const int byte_mode = shflag[0] | shflag[1] | shflag[2] | shflag[3];

  float e[8];
  float sum = 0.f;
#pragma unroll
  for (int j = 0; j < 8; ++j) {
    const int idx = tid + j * 256;
    float v = __expf(s[j] - mx);
    const int mv = byte_mode ? (int)((const unsigned char*)mask)[b * T_ + idx]
                             : ((const int*)mask)[b * T_ + idx];
    v = (mv != 0) ? v : 0.f;
    e[j] = v;
    sum += v;
  }
  for (int o = 1; o < 64; o <<= 1) sum += __shfl_xor(sum, o);
  if ((tid & 63) == 0) redsum[tid >> 6] = sum;
  __syncthreads();
  sum = redsum[0] + redsum[1] + redsum[2] + redsum[3];
  const float inv = 1.f / sum;
#pragma unroll
  for (int j = 0; j < 8; ++j)
    att[b * T_ + tid + j * 256] = e[j] * inv;
}

// ---------------------------------------------------------------------------
// Pooling on bf16 t: pp[tc][b][d] = sum att * tb
// ---------------------------------------------------------------------------
__global__ __launch_bounds__(256) void k_pool_bf(const unsigned short* __restrict__ tb,
                                                 const float* __restrict__ att,
                                                 float* __restrict__ pp) {
  const int b = blockIdx.x, tc = blockIdx.y, tid = threadIdx.x;
  const uint2* tp = (const uint2*)tb;
  float4 acc = make_float4(0.f, 0.f, 0.f, 0.f);
  const int tbase = tc * 128;
  for (int i = 0; i < 128; ++i) {
    const int ti = tbase + i;
    const float wv = att[b * T_ + ti];
    const uint2 v = tp[(size_t)(b * T_ + ti) * 256 + tid];
    acc.x += wv * bfu(v.x & 0xffffu);
    acc.y += wv * bfu(v.x >> 16);
    acc.z += wv * bfu(v.y & 0xffffu);
    acc.w += wv * bfu(v.y >> 16);
  }
  ((float4*)pp)[(size_t)tc * 8192 + b * 256 + tid] = acc;
}

// Fallback pooling on fp32 t.
__global__ __launch_bounds__(256) void k_pool_f32(const float* __restrict__ t,
                                                  const float* __restrict__ att,
                                                  float* __restrict__ pp) {
  const int b = blockIdx.x, tc = blockIdx.y, tid = threadIdx.x;
  const float4* tp = (const float4*)t;
  float4 acc = make_float4(0.f, 0.f, 0.f, 0.f);
  const int tbase = tc * 128;
  for (int i = 0; i < 128; ++i) {
    const int ti = tbase + i;
    const float w = att[b * T_ + ti];
    const float4 v = tp[(size_t)(b * T_ + ti) * 256 + tid];
    acc.x += w * v.x; acc.y += w * v.y; acc.z += w * v.z; acc.w += w * v.w;
  }
  ((float4*)pp)[(size_t)tc * 8192 + b * 256 + tid] = acc;
}

__global__ __launch_bounds__(256) void k_pool_reduce(const float* __restrict__ pp,
                                                     float* __restrict__ out) {
  const int idx = blockIdx.x * 256 + threadIdx.x;  // 0 .. 32767
  float s = 0.f;
#pragma unroll
  for (int tc = 0; tc < 16; ++tc) s += pp[tc * 32768 + idx];
  out[idx] = s;
}

// ---------------------------------------------------------------------------
extern "C" void kernel_launch(void* const* d_in, const int* in_sizes, int n_in,
                              void* d_out, int out_size, void* d_ws, size_t ws_size,
                              hipStream_t stream) {
  const float* t    = (const float*)d_in[0];
  const float* a    = (const float*)d_in[1];
  const float* b    = (const float*)d_in[2];
  const void*  mask = d_in[3];
  const float* wt   = (const float*)d_in[4];
  const float* wa   = (const float*)d_in[5];
  const float* wb   = (const float*)d_in[6];
  const float* wh   = (const float*)d_in[7];
  float* out = (float*)d_out;

  float* ws = (float*)d_ws;
  const size_t NEED_FAST = (size_t)(33554432 + 32768 + 65536 + 524288 + 524288 + 524288) * 4;
  const bool fast = ws_size >= NEED_FAST;

  if (fast) {
    unsigned short* tb = (unsigned short*)ws;          // 128 MB
    float* g     = ws + 33554432;
    float* att   = g + 32768;
    float* spart = att + 65536;                        // 524288 floats (2 MB)
    float* pp    = spart + 524288;                     // 524288 floats (2 MB)
    unsigned short* wtT = (unsigned short*)(pp + 524288);
    // gpa overlays spart (16*32768 = 524288 floats), gpb overlays pp.
    float* gpa = spart;
    float* gpb = pp;

    k_prep_small<<<1536, 256, 0, stream>>>(wt, wtT, a, b, wa, wb, gpa, gpb);
    k_gfin<<<128, 256, 0, stream>>>(gpa, gpb, wh, g);
    k_tobf16<<<2048, 256, 0, stream>>>(t, (uint2*)tb);
    k_score_fast<<<2048, 512, 0, stream>>>(tb, wtT, g, spart);
    k_softmax<<<32, 256, 0, stream>>>(spart, mask, att, 8);
    k_pool_bf<<<dim3(32, 16), 256, 0, stream>>>(tb, att, pp);
    k_pool_reduce<<<128, 256, 0, stream>>>(pp, out);
  } else {
    float* g     = ws;
    float* att   = ws + 32768;
    float* spart = ws + 98304;                         // 524288 floats
    float* pp    = ws + 622592;                        // 524288 floats
    unsigned short* wtT = (unsigned short*)(ws + 1146880);
    float* gpa = spart;
    float* gpb = pp;

    k_prep_small<<<1536, 256, 0, stream>>>(wt, wtT, a, b, wa, wb, gpa, gpb);
    k_gfin<<<128, 256, 0, stream>>>(gpa, gpb, wh, g);
    k_score_rs<<<dim3(8, 512), 256, 0, stream>>>(t, wtT, g, spart);
    k_softmax<<<32, 256, 0, stream>>>(spart, mask, att, 8);
    k_pool_f32<<<dim3(32, 16), 256, 0, stream>>>(t, att, pp);
    k_pool_reduce<<<128, 256, 0, stream>>>(pp, out);
  }
}